// Round 11
// baseline (2495.102 us; speedup 1.0000x reference)
//
#include <hip/hip_runtime.h>
#include <hip/hip_bf16.h>
#include <math.h>

#define T_ 8
#define N_ 1024
#define C_ 64
#define H_ 256
#define E_ 32768
#define NC_ 524800
#define SLACK 96
#define CLIPV 100000.0f

// amplification (measurement; production = 1)
#define REP_LSTM 12
#define REP_FC 12
#define REP_SYRK 48

__device__ __forceinline__ float sigmoidf_(float x) { return 1.0f / (1.0f + __expf(-x)); }

// ---------------- zero small state (deg, cnt, bar — contiguous) ----------------
__global__ void zero_init_kernel(float* base, int n) {
    int g = blockIdx.x * 256 + threadIdx.x;
    if (g < n) base[g] = 0.0f;
}

// ---------------- single-pass CSR build (deg,cnt pre-zeroed) ----------------
__global__ void scatter_direct_kernel(const int* __restrict__ ei, const float* __restrict__ ew,
                                      float* __restrict__ deg, int* __restrict__ cnt,
                                      int2* __restrict__ csr) {
    int g = blockIdx.x * 256 + threadIdx.x;           // T*E
    int t = g >> 15, e = g & (E_ - 1);
    int row = ei[t * 2 * E_ + e];
    int col = ei[t * 2 * E_ + E_ + e];
    float w = ew[g];
    int bin = t * N_ + col;
    atomicAdd(&deg[bin], w);
    int pos = atomicAdd(&cnt[bin], 1);
    if (pos < SLACK) {
        int2 v; v.x = row; v.y = __float_as_int(w);
        csr[bin * SLACK + pos] = v;
    }
}

// ---------------- generic 64x64 tiled SGEMM (NN, row-major) ----------------
__global__ __launch_bounds__(256) void sgemm_nn(const float* __restrict__ A,
                                                const float* __restrict__ B,
                                                float* __restrict__ C,
                                                int M, int N, int K) {
    __shared__ float As[16][68];
    __shared__ float Bs[16][68];
    int tid = threadIdx.x;
    int tx = tid & 15, ty = tid >> 4;
    int m0 = blockIdx.y * 64, n0 = blockIdx.x * 64;
    float acc[4][4] = {{0.f}};
    for (int k0 = 0; k0 < K; k0 += 16) {
        int ka = tid & 15, ma = tid >> 4;
#pragma unroll
        for (int mm = 0; mm < 64; mm += 16)
            As[ka][ma + mm] = A[(size_t)(m0 + ma + mm) * K + k0 + ka];
        int nb = tid & 63, kb = tid >> 6;
#pragma unroll
        for (int kk = 0; kk < 16; kk += 4)
            Bs[kb + kk][nb] = B[(size_t)(k0 + kb + kk) * N + n0 + nb];
        __syncthreads();
#pragma unroll
        for (int kk = 0; kk < 16; ++kk) {
            float4 a4 = *(const float4*)&As[kk][ty * 4];
            float4 b4 = *(const float4*)&Bs[kk][tx * 4];
            float a[4] = {a4.x, a4.y, a4.z, a4.w};
            float b[4] = {b4.x, b4.y, b4.z, b4.w};
#pragma unroll
            for (int i = 0; i < 4; ++i)
#pragma unroll
                for (int j = 0; j < 4; ++j) acc[i][j] += a[i] * b[j];
        }
        __syncthreads();
    }
#pragma unroll
    for (int i = 0; i < 4; ++i) {
        float4 o = make_float4(acc[i][0], acc[i][1], acc[i][2], acc[i][3]);
        *(float4*)&C[(size_t)(m0 + ty * 4 + i) * N + n0 + tx * 4] = o;
    }
}

// ---------------- GCN aggregation: 1 wave = 1 node, float4 ch, 8-way ILP ----------------
__global__ __launch_bounds__(256) void agg_kernel(const float* __restrict__ hin,
                                                  const float* __restrict__ deg,
                                                  const int* __restrict__ cnt,
                                                  const int2* __restrict__ csr,
                                                  const float* __restrict__ bias,
                                                  float* __restrict__ out) {
    __shared__ int s_src[4][SLACK];
    __shared__ float s_nrm[4][SLACK];
    int tid = threadIdx.x;
    int nd = tid >> 6, lane = tid & 63;
    int bx = blockIdx.x * 4 + nd;            // t*N + j
    int t = bx >> 10;
    int lane4 = lane * 4;
    float dj = rsqrtf(deg[bx] + 1.0f);
    int count = min(cnt[bx], SLACK);
    const float* hbase = hin + (size_t)(t * N_) * H_;
    const float* dbase = deg + t * N_;
    float4 self = *(const float4*)&hin[(size_t)bx * H_ + lane4];
    for (int u = lane; u < count; u += 64) {
        int2 v = csr[(size_t)bx * SLACK + u];
        s_src[nd][u] = v.x;
        s_nrm[nd][u] = __int_as_float(v.y) * rsqrtf(dbase[v.x] + 1.0f);
    }
    __syncthreads();
    float4 aa[8];
#pragma unroll
    for (int z = 0; z < 8; ++z) aa[z] = make_float4(0.f, 0.f, 0.f, 0.f);
    int u = 0;
    for (; u + 7 < count; u += 8) {
        int ss[8]; float nn[8]; float4 vv[8];
#pragma unroll
        for (int z = 0; z < 8; ++z) { ss[z] = s_src[nd][u + z]; nn[z] = s_nrm[nd][u + z]; }
#pragma unroll
        for (int z = 0; z < 8; ++z) vv[z] = *(const float4*)&hbase[(size_t)ss[z] * H_ + lane4];
#pragma unroll
        for (int z = 0; z < 8; ++z) {
            aa[z].x += nn[z] * vv[z].x; aa[z].y += nn[z] * vv[z].y;
            aa[z].z += nn[z] * vv[z].z; aa[z].w += nn[z] * vv[z].w;
        }
    }
    for (; u < count; ++u) {
        int s0 = s_src[nd][u]; float n0 = s_nrm[nd][u];
        float4 v0 = *(const float4*)&hbase[(size_t)s0 * H_ + lane4];
        aa[0].x += n0*v0.x; aa[0].y += n0*v0.y; aa[0].z += n0*v0.z; aa[0].w += n0*v0.w;
    }
#pragma unroll
    for (int z = 1; z < 8; ++z) {
        aa[0].x += aa[z].x; aa[0].y += aa[z].y; aa[0].z += aa[z].z; aa[0].w += aa[z].w;
    }
    float4 bi = *(const float4*)&bias[lane4];
    float4 val;
    val.x = dj * (dj * self.x + aa[0].x) + bi.x;
    val.y = dj * (dj * self.y + aa[0].y) + bi.y;
    val.z = dj * (dj * self.z + aa[0].z) + bi.z;
    val.w = dj * (dj * self.w + aa[0].w) + bi.w;
    val.x = fminf(fmaxf(val.x, 0.0f), CLIPV);
    val.y = fminf(fmaxf(val.y, 0.0f), CLIPV);
    val.z = fminf(fmaxf(val.z, 0.0f), CLIPV);
    val.w = fminf(fmaxf(val.w, 0.0f), CLIPV);
    *(float4*)&out[(size_t)bx * H_ + lane4] = val;
}

// ---------------- mean-pool partials: (t, 32-node chunk) per block ----------------
__global__ __launch_bounds__(256) void pool_kernel(const float* __restrict__ h2,
                                                   float* __restrict__ pool_part) {
    int b = blockIdx.x;                      // t*32 + c
    int t = b >> 5, c = b & 31;
    int tid = threadIdx.x;
    const float* base = h2 + ((size_t)(t * N_ + c * 32)) * H_ + tid;
    float a = 0.f;
#pragma unroll
    for (int n = 0; n < 32; ++n) a += base[(size_t)n * H_];
    pool_part[(size_t)b * H_ + tid] = a * (1.0f / 1024.0f);
}

// ---------------- fused LSTM (amplified): MALL-atomic exchange, relaxed barrier ----------------
__device__ __forceinline__ void gbar_relaxed(int* bar, int target) {
    __syncthreads();
    if (threadIdx.x == 0) {
        __threadfence_block();
        __hip_atomic_fetch_add(bar, 1, __ATOMIC_RELAXED, __HIP_MEMORY_SCOPE_AGENT);
        long spin = 0;
        while (__hip_atomic_load(bar, __ATOMIC_RELAXED, __HIP_MEMORY_SCOPE_AGENT) < target) {
            if (++spin > (1L << 27)) break;   // hang guard
        }
    }
    __syncthreads();
}

__global__ __launch_bounds__(1024) void lstm_fused_kernel(const float* __restrict__ pool_part,
                                                          const float* __restrict__ w_ih,
                                                          const float* __restrict__ w_hh,
                                                          const float* __restrict__ b_ih,
                                                          const float* __restrict__ b_hh,
                                                          float* __restrict__ gbuf,  // 2*1024
                                                          int* __restrict__ bar,     // zeroed at graph start
                                                          float* __restrict__ final_h,
                                                          int reps) {
    __shared__ float s_emb[T_][H_];
    __shared__ float s_xg[T_][256];
    __shared__ float s_h[H_];
    int tid = threadIdx.x;
    int jl = tid >> 2, q = tid & 3;        // gate index within block, k-quarter
    int j = blockIdx.x * 256 + jl;
    float4 whh[16];
    {
        const float4* wr = (const float4*)(w_hh + (size_t)j * H_ + q * 64);
#pragma unroll
        for (int r = 0; r < 16; ++r) whh[r] = wr[r];
    }
    for (int rep = 0; rep < reps; ++rep) {
        // Phase A1: partial-pool reduce -> embeddings
        for (int v = tid; v < T_ * H_; v += 1024) {
            int t = v >> 8, ch = v & 255;
            float a = 0.f;
#pragma unroll
            for (int g2 = 0; g2 < 32; ++g2) a += pool_part[(size_t)(t * 32 + g2) * H_ + ch];
            s_emb[t][ch] = fminf(fmaxf(a, -CLIPV), CLIPV);
        }
        __syncthreads();
        // Phase A2: x-gates for this block's 256 gates, all 8 steps
        {
            const float4* wr = (const float4*)(w_ih + (size_t)j * H_ + q * 64);
            float acc_t[T_] = {0.f, 0.f, 0.f, 0.f, 0.f, 0.f, 0.f, 0.f};
#pragma unroll
            for (int r = 0; r < 16; ++r) {
                float4 w = wr[r];
                int k = q * 64 + r * 4;
#pragma unroll
                for (int t = 0; t < T_; ++t)
                    acc_t[t] += w.x * s_emb[t][k] + w.y * s_emb[t][k + 1]
                              + w.z * s_emb[t][k + 2] + w.w * s_emb[t][k + 3];
            }
#pragma unroll
            for (int t = 0; t < T_; ++t) {
                acc_t[t] += __shfl_xor(acc_t[t], 1);
                acc_t[t] += __shfl_xor(acc_t[t], 2);
            }
            if (q == 0) {
                float bias = b_ih[j] + b_hh[j];
#pragma unroll
                for (int t = 0; t < T_; ++t) s_xg[t][jl] = bias + acc_t[t];
            }
        }
        __syncthreads();
        // Phase B: recurrence (MALL-atomic gate exchange)
        float c_reg = 0.f;
        for (int s = 0; s < T_; ++s) {
            if (s == 0) {
                if (tid < 256) s_h[tid] = 0.f;
            } else {
                if (tid < 256) {
                    const float* gp = gbuf + ((s - 1) & 1) * 1024;
                    float gi = __hip_atomic_load(&gp[tid],       __ATOMIC_RELAXED, __HIP_MEMORY_SCOPE_AGENT);
                    float gf = __hip_atomic_load(&gp[256 + tid], __ATOMIC_RELAXED, __HIP_MEMORY_SCOPE_AGENT);
                    float gg = __hip_atomic_load(&gp[512 + tid], __ATOMIC_RELAXED, __HIP_MEMORY_SCOPE_AGENT);
                    float go = __hip_atomic_load(&gp[768 + tid], __ATOMIC_RELAXED, __HIP_MEMORY_SCOPE_AGENT);
                    c_reg = sigmoidf_(gf) * c_reg + sigmoidf_(gi) * tanhf(gg);
                    s_h[tid] = sigmoidf_(go) * tanhf(c_reg);
                }
            }
            __syncthreads();
            float acc = 0.f;
#pragma unroll
            for (int r = 0; r < 16; ++r) {
                float4 w = whh[r];
                int k = q * 64 + r * 4;
                acc += w.x * s_h[k] + w.y * s_h[k + 1] + w.z * s_h[k + 2] + w.w * s_h[k + 3];
            }
            acc += __shfl_xor(acc, 1);
            acc += __shfl_xor(acc, 2);
            if (q == 0)
                __hip_atomic_store(&gbuf[(s & 1) * 1024 + j], s_xg[s][jl] + acc,
                                   __ATOMIC_RELAXED, __HIP_MEMORY_SCOPE_AGENT);
            gbar_relaxed(bar, 4 * (rep * T_ + s + 1));
        }
        if (blockIdx.x == 0 && tid < 256) {
            const float* gp = gbuf + ((T_ - 1) & 1) * 1024;
            float gi = __hip_atomic_load(&gp[tid],       __ATOMIC_RELAXED, __HIP_MEMORY_SCOPE_AGENT);
            float gf = __hip_atomic_load(&gp[256 + tid], __ATOMIC_RELAXED, __HIP_MEMORY_SCOPE_AGENT);
            float gg = __hip_atomic_load(&gp[512 + tid], __ATOMIC_RELAXED, __HIP_MEMORY_SCOPE_AGENT);
            float go = __hip_atomic_load(&gp[768 + tid], __ATOMIC_RELAXED, __HIP_MEMORY_SCOPE_AGENT);
            float cc = sigmoidf_(gf) * c_reg + sigmoidf_(gi) * tanhf(gg);
            final_h[tid] = sigmoidf_(go) * tanhf(cc);
        }
        __syncthreads();
    }
}

// ---------------- triangular scatter helper ----------------
__device__ __forceinline__ void store_quad(float4 v, int j0, float* __restrict__ Lm) {
    int i = (int)((sqrtf(8.0f * (float)j0 + 1.0f) - 1.0f) * 0.5f);
    while ((i + 1) * (i + 2) / 2 <= j0) ++i;
    while (i * (i + 1) / 2 > j0) --i;
    int rb = i * (i + 1) / 2, col = j0 - rb;
    if (col + 3 <= i) {
        *(float4*)&Lm[(size_t)i * 1024 + col] = v;
    } else {
        float vv[4] = {v.x, v.y, v.z, v.w};
#pragma unroll
        for (int e = 0; e < 4; ++e) {
            int jj = j0 + e;
            while ((i + 1) * (i + 2) / 2 <= jj) ++i;
            Lm[(size_t)i * 1024 + (jj - i * (i + 1) / 2)] = vv[e];
        }
    }
}

// ---------------- fc GEMV (amplified): 64 quads/block, k-split x4, LDS reduce ----------------
__global__ __launch_bounds__(256) void fc_kernel(const float* __restrict__ final_h,
                                                 const float* __restrict__ fc_w,
                                                 const float* __restrict__ fc_b,
                                                 float* __restrict__ Lm, int reps) {
    __shared__ float s_h[H_];
    __shared__ float4 s_red[256];
    int tid = threadIdx.x;
    s_h[tid] = final_h[tid];
    __syncthreads();
    const int NQ = NC_ / 4;                       // 131200 = 64 * 2050
    int lane = tid & 63, grp = tid >> 6;
    int j4 = blockIdx.x * 64 + lane;
    const float4* w4 = (const float4*)fc_w;
    int k0 = grp * 64;
    for (int rep = 0; rep < reps; ++rep) {
        float4 acc = make_float4(0.f, 0.f, 0.f, 0.f);
#pragma unroll 8
        for (int i = 0; i < 64; ++i) {
            int k = k0 + i;
            float4 w = w4[(size_t)k * NQ + j4];
            float hk = s_h[k];
            acc.x += hk * w.x; acc.y += hk * w.y; acc.z += hk * w.z; acc.w += hk * w.w;
        }
        s_red[tid] = acc;
        __syncthreads();
        if (tid < 64) {
            float4 a0 = s_red[tid], a1 = s_red[64 + tid], a2 = s_red[128 + tid], a3 = s_red[192 + tid];
            float4 b = ((const float4*)fc_b)[j4];
            float4 r;
            r.x = a0.x + a1.x + a2.x + a3.x + b.x;
            r.y = a0.y + a1.y + a2.y + a3.y + b.y;
            r.z = a0.z + a1.z + a2.z + a3.z + b.z;
            r.w = a0.w + a1.w + a2.w + a3.w + b.w;
            r.x = fminf(fmaxf(r.x, -CLIPV), CLIPV);
            r.y = fminf(fmaxf(r.y, -CLIPV), CLIPV);
            r.z = fminf(fmaxf(r.z, -CLIPV), CLIPV);
            r.w = fminf(fmaxf(r.w, -CLIPV), CLIPV);
            store_quad(r, j4 * 4, Lm);
        }
        __syncthreads();
    }
}

// ---------------- syrk (amplified): K-split x4, NON-ATOMIC partials ----------------
__global__ __launch_bounds__(256) void syrk_kernel(const float* __restrict__ L,
                                                   float* __restrict__ pbuf, int reps) {
    int b = blockIdx.x;                                    // 136 (I,J<=I) pairs
    int I = (int)((sqrtf(8.0f * b + 1.0f) - 1.0f) * 0.5f);
    while ((I + 1) * (I + 2) / 2 <= b) ++I;
    while (I * (I + 1) / 2 > b) --I;
    int J = b - I * (I + 1) / 2;
    int Klim = (J + 1) * 64;                               // L[r,k]=0 for k>r; J<=I
    int kbeg = blockIdx.y * 256;
    int kend = min(Klim, kbeg + 256);

    __shared__ float As[16][68];
    __shared__ float Bs[16][68];
    int tid = threadIdx.x;
    int tx = tid & 15, ty = tid >> 4;
    int m0 = I * 64, n0 = J * 64;
    float* slice = pbuf + ((size_t)blockIdx.y * 136 + b) * 4096;
    for (int rep = 0; rep < reps; ++rep) {
        float acc[4][4] = {{0.f}};
        for (int k0 = kbeg; k0 < kend; k0 += 16) {
            int ka = tid & 15, ma = tid >> 4;
#pragma unroll
            for (int mm = 0; mm < 64; mm += 16) {
                int rA = m0 + ma + mm, rB = n0 + ma + mm, kg = k0 + ka;
                float va = L[(size_t)rA * 1024 + kg];
                float vb = L[(size_t)rB * 1024 + kg];
                As[ka][ma + mm] = (kg <= rA) ? va : 0.f;
                Bs[ka][ma + mm] = (kg <= rB) ? vb : 0.f;
            }
            __syncthreads();
#pragma unroll
            for (int kk = 0; kk < 16; ++kk) {
                float4 a4 = *(const float4*)&As[kk][ty * 4];
                float4 b4 = *(const float4*)&Bs[kk][tx * 4];
                float a[4] = {a4.x, a4.y, a4.z, a4.w};
                float bb[4] = {b4.x, b4.y, b4.z, b4.w};
#pragma unroll
                for (int i = 0; i < 4; ++i)
#pragma unroll
                    for (int j = 0; j < 4; ++j) acc[i][j] += a[i] * bb[j];
            }
            __syncthreads();
        }
#pragma unroll
        for (int i = 0; i < 4; ++i) {
            float4 o = make_float4(acc[i][0], acc[i][1], acc[i][2], acc[i][3]);
            *(float4*)&slice[(ty * 4 + i) * 64 + tx * 4] = o;   // zero-filled if kbeg>=kend
        }
        __syncthreads();
    }
}

// ---------------- reduce 4 K-slices + write tile and its mirror ----------------
__global__ __launch_bounds__(256) void reduce_mirror_kernel(const float* __restrict__ pbuf,
                                                            float* __restrict__ Cout) {
    __shared__ float tr[64][65];
    int b = blockIdx.x;                                    // 136 pairs
    int I = (int)((sqrtf(8.0f * b + 1.0f) - 1.0f) * 0.5f);
    while ((I + 1) * (I + 2) / 2 <= b) ++I;
    while (I * (I + 1) / 2 > b) --I;
    int J = b - I * (I + 1) / 2;
    int m0 = I * 64, n0 = J * 64;
    int tid = threadIdx.x;
    const float* p0 = pbuf + (size_t)b * 4096;
#pragma unroll
    for (int e = 0; e < 16; ++e) {
        int idx = e * 256 + tid;
        float v = p0[idx] + p0[136 * 4096 + idx] + p0[2 * 136 * 4096 + idx] + p0[3 * 136 * 4096 + idx];
        int r = idx >> 6, c = idx & 63;
        tr[r][c] = v;
        Cout[(size_t)(m0 + r) * 1024 + n0 + c] = v;
    }
    if (I == J) return;
    __syncthreads();
#pragma unroll
    for (int e = 0; e < 16; ++e) {
        int idx = e * 256 + tid;
        int r = idx >> 6, c = idx & 63;
        Cout[(size_t)(n0 + r) * 1024 + m0 + c] = tr[c][r];
    }
}

// ---------------- host launch ----------------
extern "C" void kernel_launch(void* const* d_in, const int* in_sizes, int n_in,
                              void* d_out, int out_size, void* d_ws, size_t ws_size,
                              hipStream_t stream) {
    const float* xs      = (const float*)d_in[0];
    const int*   ei      = (const int*)d_in[1];
    const float* ew      = (const float*)d_in[2];
    const float* conv1_w = (const float*)d_in[3];
    const float* conv1_b = (const float*)d_in[4];
    const float* conv2_w = (const float*)d_in[5];
    const float* conv2_b = (const float*)d_in[6];
    const float* w_ih    = (const float*)d_in[7];
    const float* w_hh    = (const float*)d_in[8];
    const float* b_ih    = (const float*)d_in[9];
    const float* b_hh    = (const float*)d_in[10];
    const float* fc_w    = (const float*)d_in[11];
    const float* fc_b    = (const float*)d_in[12];
    float* out = (float*)d_out;

    // workspace layout (floats)
    float* ws = (float*)d_ws;
    size_t off = 0;
    float* xw1  = ws + off; off += (size_t)T_ * N_ * H_;      // staging (also hw2)
    float* h1   = ws + off; off += (size_t)T_ * N_ * H_;      // h1, then h2
    float* Lm   = ws + off; off += (size_t)N_ * N_;            // dense L (upper = don't-care)
    // ---- contiguous zero region start ----
    float* deg  = ws + off; off += T_ * N_;
    int*   cnt  = (int*)(ws + off); off += T_ * N_;
    int*   bar  = (int*)(ws + off); off += 256;
    int zero_elems = T_ * N_ * 2 + 256;
    float* zero_base = deg;
    // ---- contiguous zero region end ----
    float* pool_part = ws + off; off += T_ * 32 * H_;
    float* gbuf = ws + off; off += 2 * 1024;
    float* final_h = ws + off; off += 256;
    float* pbuf = ws + off; off += (size_t)4 * 136 * 4096;     // syrk partials (8.9 MB)
    int2* csr = (int2*)(ws + off); off += (size_t)T_ * N_ * SLACK * 2;
    (void)ws_size; (void)in_sizes; (void)n_in; (void)out_size;

    zero_init_kernel<<<(zero_elems + 255) / 256, 256, 0, stream>>>(zero_base, zero_elems);
    scatter_direct_kernel<<<(T_ * E_) / 256, 256, 0, stream>>>(ei, ew, deg, cnt, csr);

    // conv1: xw1 = xs @ W1
    sgemm_nn<<<dim3(H_ / 64, (T_ * N_) / 64), 256, 0, stream>>>(xs, conv1_w, xw1, T_ * N_, H_, C_);
    agg_kernel<<<T_ * N_ / 4, 256, 0, stream>>>(xw1, deg, cnt, csr, conv1_b, h1);
    // conv2: hw2 (=xw1 buffer) = h1 @ W2
    sgemm_nn<<<dim3(H_ / 64, (T_ * N_) / 64), 256, 0, stream>>>(h1, conv2_w, xw1, T_ * N_, H_, H_);
    agg_kernel<<<T_ * N_ / 4, 256, 0, stream>>>(xw1, deg, cnt, csr, conv2_b, h1);   // h2 -> h1 buf
    pool_kernel<<<T_ * 32, 256, 0, stream>>>(h1, pool_part);

    // [AMPLIFIED x12]
    lstm_fused_kernel<<<4, 1024, 0, stream>>>(pool_part, w_ih, w_hh, b_ih, b_hh, gbuf, bar, final_h, REP_LSTM);

    // [AMPLIFIED x12]
    fc_kernel<<<NC_ / 4 / 64, 256, 0, stream>>>(final_h, fc_w, fc_b, Lm, REP_FC);

    // [AMPLIFIED x48, idempotent partial writes]
    syrk_kernel<<<dim3(136, 4), 256, 0, stream>>>(Lm, pbuf, REP_SYRK);
    reduce_mirror_kernel<<<136, 256, 0, stream>>>(pbuf, out);
}

// Round 12
// 290.935 us; speedup vs baseline: 8.5761x; 8.5761x over previous
//
#include <hip/hip_runtime.h>
#include <hip/hip_bf16.h>
#include <math.h>

#define T_ 8
#define N_ 1024
#define C_ 64
#define H_ 256
#define E_ 32768
#define NC_ 524800
#define SLACK 96
#define CLIPV 100000.0f
#define WARM_BLOCKS 896

__device__ __forceinline__ float sigmoidf_(float x) { return 1.0f / (1.0f + __expf(-x)); }

// ---------------- zero small state (deg, cnt, bar, flag — contiguous) ----------------
__global__ void zero_init_kernel(float* base, int n) {
    int g = blockIdx.x * 256 + threadIdx.x;
    if (g < n) base[g] = 0.0f;
}

// ---------------- single-pass CSR build (deg,cnt pre-zeroed) ----------------
__global__ void scatter_direct_kernel(const int* __restrict__ ei, const float* __restrict__ ew,
                                      float* __restrict__ deg, int* __restrict__ cnt,
                                      int2* __restrict__ csr) {
    int g = blockIdx.x * 256 + threadIdx.x;           // T*E
    int t = g >> 15, e = g & (E_ - 1);
    int row = ei[t * 2 * E_ + e];
    int col = ei[t * 2 * E_ + E_ + e];
    float w = ew[g];
    int bin = t * N_ + col;
    atomicAdd(&deg[bin], w);
    int pos = atomicAdd(&cnt[bin], 1);
    if (pos < SLACK) {
        int2 v; v.x = row; v.y = __float_as_int(w);
        csr[bin * SLACK + pos] = v;
    }
}

// ---------------- generic 64x64 tiled SGEMM (NN, row-major) ----------------
__global__ __launch_bounds__(256) void sgemm_nn(const float* __restrict__ A,
                                                const float* __restrict__ B,
                                                float* __restrict__ C,
                                                int M, int N, int K) {
    __shared__ float As[16][68];
    __shared__ float Bs[16][68];
    int tid = threadIdx.x;
    int tx = tid & 15, ty = tid >> 4;
    int m0 = blockIdx.y * 64, n0 = blockIdx.x * 64;
    float acc[4][4] = {{0.f}};
    for (int k0 = 0; k0 < K; k0 += 16) {
        int ka = tid & 15, ma = tid >> 4;
#pragma unroll
        for (int mm = 0; mm < 64; mm += 16)
            As[ka][ma + mm] = A[(size_t)(m0 + ma + mm) * K + k0 + ka];
        int nb = tid & 63, kb = tid >> 6;
#pragma unroll
        for (int kk = 0; kk < 16; kk += 4)
            Bs[kb + kk][nb] = B[(size_t)(k0 + kb + kk) * N + n0 + nb];
        __syncthreads();
#pragma unroll
        for (int kk = 0; kk < 16; ++kk) {
            float4 a4 = *(const float4*)&As[kk][ty * 4];
            float4 b4 = *(const float4*)&Bs[kk][tx * 4];
            float a[4] = {a4.x, a4.y, a4.z, a4.w};
            float b[4] = {b4.x, b4.y, b4.z, b4.w};
#pragma unroll
            for (int i = 0; i < 4; ++i)
#pragma unroll
                for (int j = 0; j < 4; ++j) acc[i][j] += a[i] * b[j];
        }
        __syncthreads();
    }
#pragma unroll
    for (int i = 0; i < 4; ++i) {
        float4 o = make_float4(acc[i][0], acc[i][1], acc[i][2], acc[i][3]);
        *(float4*)&C[(size_t)(m0 + ty * 4 + i) * N + n0 + tx * 4] = o;
    }
}

// ---------------- GCN aggregation: 1 wave = 1 node, float4 ch, 8-way ILP ----------------
__global__ __launch_bounds__(256) void agg_kernel(const float* __restrict__ hin,
                                                  const float* __restrict__ deg,
                                                  const int* __restrict__ cnt,
                                                  const int2* __restrict__ csr,
                                                  const float* __restrict__ bias,
                                                  float* __restrict__ out) {
    __shared__ int s_src[4][SLACK];
    __shared__ float s_nrm[4][SLACK];
    int tid = threadIdx.x;
    int nd = tid >> 6, lane = tid & 63;
    int bx = blockIdx.x * 4 + nd;            // t*N + j
    int t = bx >> 10;
    int lane4 = lane * 4;
    float dj = rsqrtf(deg[bx] + 1.0f);
    int count = min(cnt[bx], SLACK);
    const float* hbase = hin + (size_t)(t * N_) * H_;
    const float* dbase = deg + t * N_;
    float4 self = *(const float4*)&hin[(size_t)bx * H_ + lane4];
    for (int u = lane; u < count; u += 64) {
        int2 v = csr[(size_t)bx * SLACK + u];
        s_src[nd][u] = v.x;
        s_nrm[nd][u] = __int_as_float(v.y) * rsqrtf(dbase[v.x] + 1.0f);
    }
    __syncthreads();
    float4 aa[8];
#pragma unroll
    for (int z = 0; z < 8; ++z) aa[z] = make_float4(0.f, 0.f, 0.f, 0.f);
    int u = 0;
    for (; u + 7 < count; u += 8) {
        int ss[8]; float nn[8]; float4 vv[8];
#pragma unroll
        for (int z = 0; z < 8; ++z) { ss[z] = s_src[nd][u + z]; nn[z] = s_nrm[nd][u + z]; }
#pragma unroll
        for (int z = 0; z < 8; ++z) vv[z] = *(const float4*)&hbase[(size_t)ss[z] * H_ + lane4];
#pragma unroll
        for (int z = 0; z < 8; ++z) {
            aa[z].x += nn[z] * vv[z].x; aa[z].y += nn[z] * vv[z].y;
            aa[z].z += nn[z] * vv[z].z; aa[z].w += nn[z] * vv[z].w;
        }
    }
    for (; u < count; ++u) {
        int s0 = s_src[nd][u]; float n0 = s_nrm[nd][u];
        float4 v0 = *(const float4*)&hbase[(size_t)s0 * H_ + lane4];
        aa[0].x += n0*v0.x; aa[0].y += n0*v0.y; aa[0].z += n0*v0.z; aa[0].w += n0*v0.w;
    }
#pragma unroll
    for (int z = 1; z < 8; ++z) {
        aa[0].x += aa[z].x; aa[0].y += aa[z].y; aa[0].z += aa[z].z; aa[0].w += aa[z].w;
    }
    float4 bi = *(const float4*)&bias[lane4];
    float4 val;
    val.x = dj * (dj * self.x + aa[0].x) + bi.x;
    val.y = dj * (dj * self.y + aa[0].y) + bi.y;
    val.z = dj * (dj * self.z + aa[0].z) + bi.z;
    val.w = dj * (dj * self.w + aa[0].w) + bi.w;
    val.x = fminf(fmaxf(val.x, 0.0f), CLIPV);
    val.y = fminf(fmaxf(val.y, 0.0f), CLIPV);
    val.z = fminf(fmaxf(val.z, 0.0f), CLIPV);
    val.w = fminf(fmaxf(val.w, 0.0f), CLIPV);
    *(float4*)&out[(size_t)bx * H_ + lane4] = val;
}

// ---------------- mean-pool partials: (t, 32-node chunk) per block ----------------
__global__ __launch_bounds__(256) void pool_kernel(const float* __restrict__ h2,
                                                   float* __restrict__ pool_part) {
    int b = blockIdx.x;                      // t*32 + c
    int t = b >> 5, c = b & 31;
    int tid = threadIdx.x;
    const float* base = h2 + ((size_t)(t * N_ + c * 32)) * H_ + tid;
    float a = 0.f;
#pragma unroll
    for (int n = 0; n < 32; ++n) a += base[(size_t)n * H_];
    pool_part[(size_t)b * H_ + tid] = a * (1.0f / 1024.0f);
}

// ---------------- relaxed MALL barrier ----------------
__device__ __forceinline__ void gbar_relaxed(int* bar, int target) {
    __syncthreads();
    if (threadIdx.x == 0) {
        __threadfence_block();
        __hip_atomic_fetch_add(bar, 1, __ATOMIC_RELAXED, __HIP_MEMORY_SCOPE_AGENT);
        long spin = 0;
        while (__hip_atomic_load(bar, __ATOMIC_RELAXED, __HIP_MEMORY_SCOPE_AGENT) < target) {
            if (++spin > (1L << 27)) break;   // hang guard
        }
    }
    __syncthreads();
}

// ---------------- triangular scatter helper ----------------
__device__ __forceinline__ void store_quad(float4 v, int j0, float* __restrict__ Lm) {
    int i = (int)((sqrtf(8.0f * (float)j0 + 1.0f) - 1.0f) * 0.5f);
    while ((i + 1) * (i + 2) / 2 <= j0) ++i;
    while (i * (i + 1) / 2 > j0) --i;
    int rb = i * (i + 1) / 2, col = j0 - rb;
    if (col + 3 <= i) {
        *(float4*)&Lm[(size_t)i * 1024 + col] = v;
    } else {
        float vv[4] = {v.x, v.y, v.z, v.w};
#pragma unroll
        for (int e = 0; e < 4; ++e) {
            int jj = j0 + e;
            while ((i + 1) * (i + 2) / 2 <= jj) ++i;
            Lm[(size_t)i * 1024 + (jj - i * (i + 1) / 2)] = vv[e];
        }
    }
}

// ---------------- fused LSTM + fc GEMV with MALL pre-warming ----------------
// Blocks 0..15: LSTM (16 blocks x 64 gates, relaxed-MALL barrier).
// Blocks 16..2065: fc. First WARM_BLOCKS warm their fc_w slice into Infinity
// Cache while LSTM runs (HBM otherwise idle), then all run the GEMV once
// final_h is published via a MALL flag.
__global__ __launch_bounds__(256) void lstm_fc_kernel(const float* __restrict__ pool_part,
                                                      const float* __restrict__ w_ih,
                                                      const float* __restrict__ w_hh,
                                                      const float* __restrict__ b_ih,
                                                      const float* __restrict__ b_hh,
                                                      const float* __restrict__ fc_w,
                                                      const float* __restrict__ fc_b,
                                                      float* __restrict__ gbuf,   // 2*1024
                                                      int* __restrict__ bar,      // zeroed
                                                      int* __restrict__ flag,     // zeroed
                                                      float* __restrict__ final_h,
                                                      float* __restrict__ Lm) {
    __shared__ float s_emb[T_][H_];          // lstm emb | fc: s_red alias
    __shared__ float s_h[H_];
    __shared__ float s_xg[T_][64];
    int b = blockIdx.x, tid = threadIdx.x;
    if (b < 16) {
        // ---------------- LSTM role ----------------
        int jl = tid >> 2, q = tid & 3;      // gate-in-block, k-quarter
        int j = b * 64 + jl;
        float4 whh[16];
        {
            const float4* wr = (const float4*)(w_hh + (size_t)j * H_ + q * 64);
#pragma unroll
            for (int r = 0; r < 16; ++r) whh[r] = wr[r];
        }
        // A1: pool-reduce -> embeddings (redundant per block)
        for (int v = tid; v < T_ * H_; v += 256) {
            int t = v >> 8, ch = v & 255;
            float a = 0.f;
#pragma unroll
            for (int g2 = 0; g2 < 32; ++g2) a += pool_part[(size_t)(t * 32 + g2) * H_ + ch];
            s_emb[t][ch] = fminf(fmaxf(a, -CLIPV), CLIPV);
        }
        __syncthreads();
        // A2: x-gates for this block's 64 gates, all 8 steps
        {
            const float4* wr = (const float4*)(w_ih + (size_t)j * H_ + q * 64);
            float acc_t[T_] = {0.f, 0.f, 0.f, 0.f, 0.f, 0.f, 0.f, 0.f};
#pragma unroll
            for (int r = 0; r < 16; ++r) {
                float4 w = wr[r];
                int k = q * 64 + r * 4;
#pragma unroll
                for (int t = 0; t < T_; ++t)
                    acc_t[t] += w.x * s_emb[t][k] + w.y * s_emb[t][k + 1]
                              + w.z * s_emb[t][k + 2] + w.w * s_emb[t][k + 3];
            }
#pragma unroll
            for (int t = 0; t < T_; ++t) {
                acc_t[t] += __shfl_xor(acc_t[t], 1);
                acc_t[t] += __shfl_xor(acc_t[t], 2);
            }
            if (q == 0) {
                float bias = b_ih[j] + b_hh[j];
#pragma unroll
                for (int t = 0; t < T_; ++t) s_xg[t][jl] = bias + acc_t[t];
            }
        }
        __syncthreads();
        // B: recurrence (gates via MALL atomics)
        float c_reg = 0.f;
        for (int s = 0; s < T_; ++s) {
            if (s == 0) {
                s_h[tid] = 0.f;
            } else {
                const float* gp = gbuf + ((s - 1) & 1) * 1024;
                float gi = __hip_atomic_load(&gp[tid],       __ATOMIC_RELAXED, __HIP_MEMORY_SCOPE_AGENT);
                float gf = __hip_atomic_load(&gp[256 + tid], __ATOMIC_RELAXED, __HIP_MEMORY_SCOPE_AGENT);
                float gg = __hip_atomic_load(&gp[512 + tid], __ATOMIC_RELAXED, __HIP_MEMORY_SCOPE_AGENT);
                float go = __hip_atomic_load(&gp[768 + tid], __ATOMIC_RELAXED, __HIP_MEMORY_SCOPE_AGENT);
                c_reg = sigmoidf_(gf) * c_reg + sigmoidf_(gi) * tanhf(gg);
                s_h[tid] = sigmoidf_(go) * tanhf(c_reg);
            }
            __syncthreads();
            float acc = 0.f;
#pragma unroll
            for (int r = 0; r < 16; ++r) {
                float4 w = whh[r];
                int k = q * 64 + r * 4;
                acc += w.x * s_h[k] + w.y * s_h[k + 1] + w.z * s_h[k + 2] + w.w * s_h[k + 3];
            }
            acc += __shfl_xor(acc, 1);
            acc += __shfl_xor(acc, 2);
            if (q == 0)
                __hip_atomic_store(&gbuf[(s & 1) * 1024 + j], s_xg[s][jl] + acc,
                                   __ATOMIC_RELAXED, __HIP_MEMORY_SCOPE_AGENT);
            gbar_relaxed(bar, 16 * (s + 1));
        }
        if (b == 0) {
            const float* gp = gbuf + ((T_ - 1) & 1) * 1024;
            float gi = __hip_atomic_load(&gp[tid],       __ATOMIC_RELAXED, __HIP_MEMORY_SCOPE_AGENT);
            float gf = __hip_atomic_load(&gp[256 + tid], __ATOMIC_RELAXED, __HIP_MEMORY_SCOPE_AGENT);
            float gg = __hip_atomic_load(&gp[512 + tid], __ATOMIC_RELAXED, __HIP_MEMORY_SCOPE_AGENT);
            float go = __hip_atomic_load(&gp[768 + tid], __ATOMIC_RELAXED, __HIP_MEMORY_SCOPE_AGENT);
            float cc = sigmoidf_(gf) * c_reg + sigmoidf_(gi) * tanhf(gg);
            __hip_atomic_store(&final_h[tid], sigmoidf_(go) * tanhf(cc),
                               __ATOMIC_RELAXED, __HIP_MEMORY_SCOPE_AGENT);
            __syncthreads();       // drains all 4 waves' stores to MALL
            if (tid == 0)
                __hip_atomic_store(flag, 1, __ATOMIC_RELAXED, __HIP_MEMORY_SCOPE_AGENT);
        }
    } else {
        // ---------------- fc role ----------------
        int fb = b - 16;                          // 0..2049
        int lane = tid & 63, grp = tid >> 6;
        int j4 = fb * 64 + lane;
        const int NQ = NC_ / 4;                   // 131200 = 64 * 2050
        const float4* w4 = (const float4*)fc_w;
        int k0 = grp * 64;
        // warm own slice into Infinity Cache during LSTM (bounded under MALL size)
        float dummy = 0.f;
        if (fb < WARM_BLOCKS) {
            float d0 = 0.f, d1 = 0.f, d2 = 0.f, d3 = 0.f;
            for (int i = 0; i < 64; i += 4) {
                float4 a = w4[(size_t)(k0 + i) * NQ + j4];
                float4 bq = w4[(size_t)(k0 + i + 1) * NQ + j4];
                float4 cq = w4[(size_t)(k0 + i + 2) * NQ + j4];
                float4 dq = w4[(size_t)(k0 + i + 3) * NQ + j4];
                d0 += a.x + a.y + a.z + a.w;
                d1 += bq.x + bq.y + bq.z + bq.w;
                d2 += cq.x + cq.y + cq.z + cq.w;
                d3 += dq.x + dq.y + dq.z + dq.w;
            }
            dummy = (d0 + d1) + (d2 + d3);
        }
        asm volatile("" :: "v"(dummy));           // keep warm loads live
        // wait for final_h
        if (tid == 0) {
            int spin = 0;
            while (!__hip_atomic_load(flag, __ATOMIC_RELAXED, __HIP_MEMORY_SCOPE_AGENT)) {
                __builtin_amdgcn_s_sleep(8);
                if (++spin > (1 << 20)) break;    // hang guard
            }
        }
        __syncthreads();
        s_h[tid] = __hip_atomic_load(&final_h[tid], __ATOMIC_RELAXED, __HIP_MEMORY_SCOPE_AGENT);
        __syncthreads();
        float4 acc = make_float4(0.f, 0.f, 0.f, 0.f);
#pragma unroll 8
        for (int i = 0; i < 64; ++i) {
            int k = k0 + i;
            float4 w = w4[(size_t)k * NQ + j4];
            float hk = s_h[k];
            acc.x += hk * w.x; acc.y += hk * w.y; acc.z += hk * w.z; acc.w += hk * w.w;
        }
        float4* s_red = (float4*)&s_emb[0][0];
        s_red[tid] = acc;
        __syncthreads();
        if (tid < 64) {
            float4 a0 = s_red[tid], a1 = s_red[64 + tid], a2 = s_red[128 + tid], a3 = s_red[192 + tid];
            float4 bb = ((const float4*)fc_b)[j4];
            float4 r;
            r.x = a0.x + a1.x + a2.x + a3.x + bb.x;
            r.y = a0.y + a1.y + a2.y + a3.y + bb.y;
            r.z = a0.z + a1.z + a2.z + a3.z + bb.z;
            r.w = a0.w + a1.w + a2.w + a3.w + bb.w;
            r.x = fminf(fmaxf(r.x, -CLIPV), CLIPV);
            r.y = fminf(fmaxf(r.y, -CLIPV), CLIPV);
            r.z = fminf(fmaxf(r.z, -CLIPV), CLIPV);
            r.w = fminf(fmaxf(r.w, -CLIPV), CLIPV);
            store_quad(r, j4 * 4, Lm);
        }
    }
}

// ---------------- syrk: K-split x8, non-atomic partials, masked triangular loads ----------------
__global__ __launch_bounds__(256) void syrk_kernel(const float* __restrict__ L,
                                                   float* __restrict__ pbuf) {
    int b = blockIdx.x;                                    // 136 (I,J<=I) pairs
    int I = (int)((sqrtf(8.0f * b + 1.0f) - 1.0f) * 0.5f);
    while ((I + 1) * (I + 2) / 2 <= b) ++I;
    while (I * (I + 1) / 2 > b) --I;
    int J = b - I * (I + 1) / 2;
    int Klim = (J + 1) * 64;                               // L[r,k]=0 for k>r; J<=I
    int kbeg = blockIdx.y * 128;
    int kend = min(Klim, kbeg + 128);

    __shared__ float As[16][68];
    __shared__ float Bs[16][68];
    int tid = threadIdx.x;
    int tx = tid & 15, ty = tid >> 4;
    int m0 = I * 64, n0 = J * 64;
    float* slice = pbuf + ((size_t)blockIdx.y * 136 + b) * 4096;
    float acc[4][4] = {{0.f}};
    for (int k0 = kbeg; k0 < kend; k0 += 16) {
        int ka = tid & 15, ma = tid >> 4;
#pragma unroll
        for (int mm = 0; mm < 64; mm += 16) {
            int rA = m0 + ma + mm, rB = n0 + ma + mm, kg = k0 + ka;
            float va = L[(size_t)rA * 1024 + kg];
            float vb = L[(size_t)rB * 1024 + kg];
            As[ka][ma + mm] = (kg <= rA) ? va : 0.f;
            Bs[ka][ma + mm] = (kg <= rB) ? vb : 0.f;
        }
        __syncthreads();
#pragma unroll
        for (int kk = 0; kk < 16; ++kk) {
            float4 a4 = *(const float4*)&As[kk][ty * 4];
            float4 b4 = *(const float4*)&Bs[kk][tx * 4];
            float a[4] = {a4.x, a4.y, a4.z, a4.w};
            float bb[4] = {b4.x, b4.y, b4.z, b4.w};
#pragma unroll
            for (int i = 0; i < 4; ++i)
#pragma unroll
                for (int j = 0; j < 4; ++j) acc[i][j] += a[i] * bb[j];
        }
        __syncthreads();
    }
#pragma unroll
    for (int i = 0; i < 4; ++i) {
        float4 o = make_float4(acc[i][0], acc[i][1], acc[i][2], acc[i][3]);
        *(float4*)&slice[(ty * 4 + i) * 64 + tx * 4] = o;   // zeros when kbeg>=kend
    }
}

// ---------------- reduce 8 K-slices + write tile and its mirror ----------------
__global__ __launch_bounds__(256) void reduce_mirror_kernel(const float* __restrict__ pbuf,
                                                            float* __restrict__ Cout) {
    __shared__ float tr[64][65];
    int b = blockIdx.x;                                    // 136 pairs
    int I = (int)((sqrtf(8.0f * b + 1.0f) - 1.0f) * 0.5f);
    while ((I + 1) * (I + 2) / 2 <= b) ++I;
    while (I * (I + 1) / 2 > b) --I;
    int J = b - I * (I + 1) / 2;
    int m0 = I * 64, n0 = J * 64;
    int tid = threadIdx.x;
    const float* p0 = pbuf + (size_t)b * 4096;
#pragma unroll
    for (int e = 0; e < 16; ++e) {
        int idx = e * 256 + tid;
        float v = 0.f;
#pragma unroll
        for (int s = 0; s < 8; ++s) v += p0[(size_t)s * 136 * 4096 + idx];
        int r = idx >> 6, c = idx & 63;
        tr[r][c] = v;
        Cout[(size_t)(m0 + r) * 1024 + n0 + c] = v;
    }
    if (I == J) return;
    __syncthreads();
#pragma unroll
    for (int e = 0; e < 16; ++e) {
        int idx = e * 256 + tid;
        int r = idx >> 6, c = idx & 63;
        Cout[(size_t)(n0 + r) * 1024 + m0 + c] = tr[c][r];
    }
}

// ---------------- host launch ----------------
extern "C" void kernel_launch(void* const* d_in, const int* in_sizes, int n_in,
                              void* d_out, int out_size, void* d_ws, size_t ws_size,
                              hipStream_t stream) {
    const float* xs      = (const float*)d_in[0];
    const int*   ei      = (const int*)d_in[1];
    const float* ew      = (const float*)d_in[2];
    const float* conv1_w = (const float*)d_in[3];
    const float* conv1_b = (const float*)d_in[4];
    const float* conv2_w = (const float*)d_in[5];
    const float* conv2_b = (const float*)d_in[6];
    const float* w_ih    = (const float*)d_in[7];
    const float* w_hh    = (const float*)d_in[8];
    const float* b_ih    = (const float*)d_in[9];
    const float* b_hh    = (const float*)d_in[10];
    const float* fc_w    = (const float*)d_in[11];
    const float* fc_b    = (const float*)d_in[12];
    float* out = (float*)d_out;

    // workspace layout (floats)
    float* ws = (float*)d_ws;
    size_t off = 0;
    float* xw1  = ws + off; off += (size_t)T_ * N_ * H_;      // staging (also hw2)
    float* h1   = ws + off; off += (size_t)T_ * N_ * H_;      // h1, then h2
    float* Lm   = ws + off; off += (size_t)N_ * N_;            // dense L (upper = don't-care)
    // ---- contiguous zero region start ----
    float* deg  = ws + off; off += T_ * N_;
    int*   cnt  = (int*)(ws + off); off += T_ * N_;
    int*   bar  = (int*)(ws + off); off += 256;
    int*   flag = (int*)(ws + off); off += 64;
    int zero_elems = T_ * N_ * 2 + 256 + 64;
    float* zero_base = deg;
    // ---- contiguous zero region end ----
    float* pool_part = ws + off; off += T_ * 32 * H_;
    float* gbuf = ws + off; off += 2 * 1024;
    float* final_h = ws + off; off += 256;
    float* pbuf = ws + off; off += (size_t)8 * 136 * 4096;     // syrk partials (17.8 MB)
    int2* csr = (int2*)(ws + off); off += (size_t)T_ * N_ * SLACK * 2;
    (void)ws_size; (void)in_sizes; (void)n_in; (void)out_size;

    zero_init_kernel<<<(zero_elems + 255) / 256, 256, 0, stream>>>(zero_base, zero_elems);
    scatter_direct_kernel<<<(T_ * E_) / 256, 256, 0, stream>>>(ei, ew, deg, cnt, csr);

    // conv1: xw1 = xs @ W1
    sgemm_nn<<<dim3(H_ / 64, (T_ * N_) / 64), 256, 0, stream>>>(xs, conv1_w, xw1, T_ * N_, H_, C_);
    agg_kernel<<<T_ * N_ / 4, 256, 0, stream>>>(xw1, deg, cnt, csr, conv1_b, h1);
    // conv2: hw2 (=xw1 buffer) = h1 @ W2
    sgemm_nn<<<dim3(H_ / 64, (T_ * N_) / 64), 256, 0, stream>>>(h1, conv2_w, xw1, T_ * N_, H_, H_);
    agg_kernel<<<T_ * N_ / 4, 256, 0, stream>>>(xw1, deg, cnt, csr, conv2_b, h1);   // h2 -> h1 buf
    pool_kernel<<<T_ * 32, 256, 0, stream>>>(h1, pool_part);

    // fused LSTM (blocks 0..15) + fc GEMV with MALL warming (blocks 16..2065)
    lstm_fc_kernel<<<16 + NC_ / 4 / 64, 256, 0, stream>>>(pool_part, w_ih, w_hh, b_ih, b_hh,
                                                          fc_w, fc_b, gbuf, bar, flag, final_h, Lm);

    syrk_kernel<<<dim3(136, 8), 256, 0, stream>>>(Lm, pbuf);
    reduce_mirror_kernel<<<136, 256, 0, stream>>>(pbuf, out);
}